// Round 2
// baseline (538.402 us; speedup 1.0000x reference)
//
#include <hip/hip_runtime.h>

// SPDUnVectorize: out[b,i,j] = x[b, triu_index(min(i,j), max(i,j))]
// n = 256, L = n(n+1)/2 = 32896. Pure gather, memory-bound.
//
// triu row-major index for i<=j: rowoff(i) + (j-i), rowoff(i) = i*n - i*(i-1)/2.

constexpr int N = 256;
constexpr int LTRI = 32896;          // N*(N+1)/2
constexpr int F4_PER_MAT = (N * N) / 4;   // 16384 float4 per matrix
constexpr int F4_PER_ROW = N / 4;         // 64 float4 per row

__global__ __launch_bounds__(256) void spd_unvec_kernel(
    const float* __restrict__ x, float4* __restrict__ out, int total4) {
  const int stride = gridDim.x * blockDim.x;
  for (int t = blockIdx.x * blockDim.x + threadIdx.x; t < total4; t += stride) {
    const int b = t >> 14;                 // / F4_PER_MAT
    const int f = t & (F4_PER_MAT - 1);
    const int i = f >> 6;                  // / F4_PER_ROW
    const int j0 = (f & (F4_PER_ROW - 1)) << 2;

    const float* __restrict__ xb = x + (size_t)b * LTRI;
    // upper index base: rowoff(i) - i, so idx = base + j for j >= i
    const int baseU = i * N - (i * (i - 1)) / 2 - i;

    float r[4];
#pragma unroll
    for (int k = 0; k < 4; ++k) {
      const int j = j0 + k;
      int idx;
      if (j >= i) {
        idx = baseU + j;                          // coalesced along j
      } else {
        idx = j * N - (j * (j - 1)) / 2 + (i - j); // strided, L3-resident
      }
      r[k] = xb[idx];
    }
    float4 v;
    v.x = r[0]; v.y = r[1]; v.z = r[2]; v.w = r[3];
    out[t] = v;
  }
}

extern "C" void kernel_launch(void* const* d_in, const int* in_sizes, int n_in,
                              void* d_out, int out_size, void* d_ws, size_t ws_size,
                              hipStream_t stream) {
  const float* x = (const float*)d_in[0];
  float4* out = (float4*)d_out;

  const int B = in_sizes[0] / LTRI;           // 1024 for the reference shapes
  const int total4 = B * F4_PER_MAT;          // 16,777,216

  const int threads = 256;
  int blocks = (total4 + threads - 1) / threads;
  if (blocks > 8192) blocks = 8192;           // grid-stride the rest

  spd_unvec_kernel<<<blocks, threads, 0, stream>>>(x, out, total4);
}

// Round 7
// 355.977 us; speedup vs baseline: 1.5125x; 1.5125x over previous
//
#include <hip/hip_runtime.h>

// SPDUnVectorize: out[b,i,j] = x[b, triu_index(min(i,j), max(i,j))]
// n = 256, L = n(n+1)/2 = 32896. Pure gather, memory-bound.
//
// Round-3 structure: one workgroup per batch matrix. Stage the 128.5 KB
// triangle in LDS (read each HBM byte exactly once, on exactly one XCD),
// then write all 256 KB of output coalesced, serving mirror reads from LDS.
// Round-2 evidence: FETCH_SIZE was 4.7x input (XCD duplication x cache-line
// waste on strided lower-triangle reads). This kernel makes reads minimal.

constexpr int N = 256;
constexpr int LTRI = 32896;              // N*(N+1)/2 floats
constexpr int LTRI4 = LTRI / 4;          // 8224 float4
constexpr int F4_PER_MAT = (N * N) / 4;  // 16384 float4 out per matrix
constexpr int THREADS = 1024;            // 16 waves/CU (LDS caps us at 1 wg/CU)

__global__ __launch_bounds__(THREADS) void spd_unvec_lds_kernel(
    const float* __restrict__ x, float4* __restrict__ out) {
  __shared__ float lds[LTRI];            // 131584 B of the 160 KiB LDS

  const int b = blockIdx.x;
  const int tid = threadIdx.x;

  // ---- stage triangle: coalesced float4, each byte read once ----
  const float4* __restrict__ src = (const float4*)(x + (size_t)b * LTRI);
  float4* __restrict__ lds4 = (float4*)lds;
  for (int t = tid; t < LTRI4; t += THREADS) {
    lds4[t] = src[t];
  }
  __syncthreads();

  // ---- write output: one row per wave, coalesced float4 stores ----
  float4* __restrict__ ob = out + (size_t)b * F4_PER_MAT;
#pragma unroll
  for (int w = 0; w < F4_PER_MAT / THREADS; ++w) {
    const int f = tid + (w << 10);       // 0..16383
    const int i = f >> 6;                // wave-uniform row
    const int j0 = (f & 63) << 2;
    const int baseU = i * N - (i * (i - 1)) / 2 - i;  // + j for j >= i

    float r[4];
#pragma unroll
    for (int k = 0; k < 4; ++k) {
      const int j = j0 + k;
      const int idxU = baseU + j;
      const int idxL = j * N - (j * (j - 1)) / 2 + (i - j);
      r[k] = lds[j >= i ? idxU : idxL];
    }
    float4 v;
    v.x = r[0]; v.y = r[1]; v.z = r[2]; v.w = r[3];
    ob[f] = v;
  }
}

extern "C" void kernel_launch(void* const* d_in, const int* in_sizes, int n_in,
                              void* d_out, int out_size, void* d_ws, size_t ws_size,
                              hipStream_t stream) {
  const float* x = (const float*)d_in[0];
  float4* out = (float4*)d_out;

  const int B = in_sizes[0] / LTRI;      // 1024 for the reference shapes

  spd_unvec_lds_kernel<<<B, THREADS, 0, stream>>>(x, out);
}